// Round 14
// baseline (1324.317 us; speedup 1.0000x reference)
//
#include <hip/hip_runtime.h>
#include <hip/hip_bf16.h>

constexpr int B = 4, T = 8, N = 4096, C0 = 64, C1 = 128;
constexpr int M = 1024, KNN = 32;
constexpr int NCONS = 480;        // consumer blocks
constexpr int NBLK = 32 + NCONS;  // 512 total
constexpr int SMEM_BYTES = 49408;

typedef __attribute__((ext_vector_type(8))) short short8;
typedef __attribute__((ext_vector_type(4))) float f32x4;

__device__ __forceinline__ unsigned short f2bf(float x) {
  unsigned u = __float_as_uint(x);
  u = u + 0x7FFFu + ((u >> 16) & 1u);
  return (unsigned short)(u >> 16);
}
__device__ __forceinline__ float bf2f(unsigned short h) {
  return __uint_as_float((unsigned)h << 16);
}
__device__ __forceinline__ short f2bf_rn(float x) {
  union { __hip_bfloat16 b; unsigned short u; } v;
  v.b = __float2bfloat16(x);
  return (short)v.u;
}

template <int CTRL>
__device__ __forceinline__ float dppf(float x) {
  return __int_as_float(__builtin_amdgcn_update_dpp(0, __float_as_int(x), CTRL, 0xF, 0xF, true));
}
template <int CTRL>
__device__ __forceinline__ int dppi(int x) {
  return __builtin_amdgcn_update_dpp(0, x, CTRL, 0xF, 0xF, true);
}
template <int CTRL>
__device__ __forceinline__ unsigned long long dppu64(unsigned long long x) {
  unsigned lo = (unsigned)dppi<CTRL>((int)(unsigned)x);
  unsigned hi = (unsigned)dppi<CTRL>((int)(unsigned)(x >> 32));
  return ((unsigned long long)hi << 32) | lo;
}
__device__ __forceinline__ void kmerge(unsigned long long& a, unsigned long long b) {
  if (b > a) a = b;
}
__device__ __forceinline__ unsigned long long kmax(unsigned long long a, unsigned long long b) {
  return b > a ? b : a;
}

// coherent cross-XCD primitives
__device__ __forceinline__ void aStoreF(float* p, float v) {
  __hip_atomic_store(p, v, __ATOMIC_RELAXED, __HIP_MEMORY_SCOPE_AGENT);
}
__device__ __forceinline__ float aLoadF(const float* p) {
  return __hip_atomic_load(p, __ATOMIC_RELAXED, __HIP_MEMORY_SCOPE_AGENT);
}
__device__ __forceinline__ void aStoreRelI(int* p, int v) {
  __hip_atomic_store(p, v, __ATOMIC_RELEASE, __HIP_MEMORY_SCOPE_AGENT);
}
__device__ __forceinline__ int aLoadAcqI(const int* p) {
  return __hip_atomic_load(p, __ATOMIC_ACQUIRE, __HIP_MEMORY_SCOPE_AGENT);
}

// ---------------- prep: WfT[c][o] = Wf[o][c] --------------------------------
__global__ __launch_bounds__(256) void prep_wft(const float* __restrict__ Wf,
                                                float* __restrict__ WfT) {
  int t = blockIdx.x * 256 + threadIdx.x;
  if (t < 64 * 64) WfT[t] = Wf[(t & 63) * 64 + (t >> 6)];
}

// ---------------- prep: W1 -> MFMA A-fragment-ordered bf16 hi/lo ------------
__global__ __launch_bounds__(256) void prep_w1frag(const float* __restrict__ W1,
                                                   unsigned short* __restrict__ w1hi,
                                                   unsigned short* __restrict__ w1lo) {
  int t = blockIdx.x * 256 + threadIdx.x;
  if (t >= 8192) return;
  int j = t & 7, lane = (t >> 3) & 63, mt = (t >> 9) & 7, kt = t >> 12;
  int row = mt * 16 + (lane & 15);
  int k = kt * 32 + (lane >> 4) * 8 + j;
  float v = W1[row * 64 + k];
  unsigned short hi = f2bf(v);
  w1hi[t] = hi;
  w1lo[t] = f2bf(v - bf2f(hi));
}

// ---------------- standalone rff: RFFh[n] = bf16(relu(Wf @ f_n)) ------------
__global__ __launch_bounds__(256) void rff_kernel(const float* __restrict__ f,
                                                  const float* __restrict__ WfT,
                                                  unsigned short* __restrict__ RFFh) {
  __shared__ float tile[64][65];
  int bt = blockIdx.y;
  int n0 = blockIdx.x * 64;
  const float* src = f + (size_t)bt * C0 * N;
  int tx = threadIdx.x & 63, ty = threadIdx.x >> 6;
  for (int r = ty; r < 64; r += 4)
    tile[r][tx] = src[(size_t)r * N + n0 + tx];
  __syncthreads();
  float acc[16];
#pragma unroll
  for (int oo = 0; oo < 16; ++oo) acc[oo] = 0.f;
  int obase = ty * 16;
#pragma unroll 4
  for (int c = 0; c < 64; ++c) {
    float fv = tile[c][tx];
    const float* wr = WfT + c * 64 + obase;
#pragma unroll
    for (int oo = 0; oo < 16; ++oo) acc[oo] = fmaf(fv, wr[oo], acc[oo]);
  }
  __syncthreads();
#pragma unroll
  for (int oo = 0; oo < 16; ++oo) tile[obase + oo][tx] = fmaxf(acc[oo], 0.f);
  __syncthreads();
  unsigned short* dst = RFFh + ((size_t)bt * N + n0) * 64;
  for (int r = ty; r < 64; r += 4)
    dst[(size_t)r * 64 + tx] = f2bf(tile[tx][r]);
}

// ---------------- fps producer: priority-3 waves, atomic publication --------
__device__ void fps_body(char* smem, const float* __restrict__ xyz,
                         float* __restrict__ anchors, int* __restrict__ progress, int bt) {
  __builtin_amdgcn_s_setprio(3);
  float* xs = (float*)smem;  // 16 KB
  float* ys = xs + N;        // 16 KB
  float* zs = ys + N;        // 16 KB
  unsigned long long* wslot = (unsigned long long*)(smem + 49152);
  const float* p = xyz + (size_t)bt * N * 3;
  int tid = threadIdx.x;
  int lane = tid & 63, w = tid >> 6;
  for (int i = tid; i < N; i += 256) {
    xs[i] = p[i * 3 + 0];
    ys[i] = p[i * 3 + 1];
    zs[i] = p[i * 3 + 2];
  }
  __syncthreads();
  float X[16], Y[16], Z[16], D[16];
  unsigned inv[16];
#pragma unroll
  for (int j = 0; j < 16; ++j) {
    X[j] = xs[j * 256 + tid];
    Y[j] = ys[j * 256 + tid];
    Z[j] = zs[j * 256 + tid];
    D[j] = 1e10f;
    inv[j] = ~(unsigned)(j * 256 + tid);
  }
  if (tid == 0) {
    float* a0 = anchors + (size_t)bt * M * 3;
    aStoreF(a0 + 0, xs[0]);
    aStoreF(a0 + 1, ys[0]);
    aStoreF(a0 + 2, zs[0]);
  }
  int lidx = 0;
  for (int s = 1; s < M; ++s) {
    float lx = xs[lidx], ly = ys[lidx], lz = zs[lidx];
    if (tid == 0) {
      if (s > 1) {
        float* ap = anchors + ((size_t)(bt * M + s - 1)) * 3;
        aStoreF(ap + 0, lx);
        aStoreF(ap + 1, ly);
        aStoreF(ap + 2, lz);
      }
      if ((s & 31) == 0) aStoreRelI(&progress[bt], s);
    }
    unsigned long long k[16];
#pragma unroll
    for (int j = 0; j < 16; ++j) {
      float dx = __fsub_rn(X[j], lx);
      float dy = __fsub_rn(Y[j], ly);
      float dz = __fsub_rn(Z[j], lz);
      float d = __fadd_rn(__fadd_rn(__fmul_rn(dx, dx), __fmul_rn(dy, dy)), __fmul_rn(dz, dz));
      float nd = fminf(D[j], d);
      D[j] = nd;
      k[j] = ((unsigned long long)__float_as_uint(nd) << 32) | inv[j];
    }
#pragma unroll
    for (int st = 8; st >= 1; st >>= 1)
#pragma unroll
      for (int j = 0; j < st; ++j) kmerge(k[j], k[j + st]);
    unsigned long long best = k[0];
    kmerge(best, dppu64<0xB1>(best));
    kmerge(best, dppu64<0x4E>(best));
    kmerge(best, dppu64<0x141>(best));
    kmerge(best, dppu64<0x140>(best));
    kmerge(best, dppu64<0x142>(best));  // row_bcast15
    kmerge(best, dppu64<0x143>(best));  // row_bcast31 -> lanes 48-63 = wave max
    int buf = s & 1;
    if (lane == 63) wslot[buf * 4 + w] = best;
    asm volatile("s_waitcnt lgkmcnt(0)" ::: "memory");
    __builtin_amdgcn_s_barrier();
    __builtin_amdgcn_sched_barrier(0);
    const ulonglong2* ws2 = (const ulonglong2*)&wslot[buf * 4];
    ulonglong2 a0 = ws2[0], a1 = ws2[1];
    unsigned long long g = kmax(kmax(a0.x, a0.y), kmax(a1.x, a1.y));
    lidx = (int)(~(unsigned)g);
  }
  if (tid == 0) {
    float* ap = anchors + ((size_t)(bt * M + M - 1)) * 3;
    aStoreF(ap + 0, xs[lidx]);
    aStoreF(ap + 1, ys[lidx]);
    aStoreF(ap + 2, zs[lidx]);
    aStoreRelI(&progress[bt], M);
  }
  __builtin_amdgcn_s_setprio(0);
}

// ---------------- ball query: one wave, result into LDS ---------------------
__device__ void ballq_one(const float* __restrict__ pts, float ax, float ay, float az,
                          int* outp) {
  const float R2 = 0.04f;
  int lane = threadIdx.x & 63;
  int cnt = 0, first = 0;
  for (int c = 0; c < N / 64 && cnt < KNN; ++c) {
    int pi = c * 64 + lane;
    const float* pp = pts + (size_t)pi * 3;
    float dx = __fsub_rn(ax, pp[0]);
    float dy = __fsub_rn(ay, pp[1]);
    float dz = __fsub_rn(az, pp[2]);
    float d2 = __fadd_rn(__fadd_rn(__fmul_rn(dx, dx), __fmul_rn(dy, dy)), __fmul_rn(dz, dz));
    bool hit = d2 < R2;
    unsigned long long mask = __ballot(hit);
    if (cnt == 0 && mask) first = c * 64 + (int)__builtin_ctzll(mask);
    int prefix = (int)__popcll(mask & ((1ull << lane) - 1ull));
    int slot = cnt + prefix;
    if (hit && slot < KNN) outp[slot] = pi;
    cnt += (int)__popcll(mask);
  }
  int cntK = cnt < KNN ? cnt : KNN;
  int fill = (cnt == 0) ? 0 : first;
  if (lane < KNN && lane >= cntK) outp[lane] = fill;
}

// ---------------- consumer: DS-lean -- A-fragments and Wd from global -------
__device__ void consumer_body(char* smem, const float* __restrict__ xyz,
                              const float* __restrict__ anchors,
                              const unsigned short* __restrict__ RFFh,
                              const unsigned short* __restrict__ w1hi,
                              const unsigned short* __restrict__ w1lo,
                              const float* __restrict__ Wd,
                              float* __restrict__ out_feats,
                              int* __restrict__ progress, int cid) {
  int tid = threadIdx.x;
  float* anc_lds = (float*)smem;                         // 64 B
  int* idx_lds = (int*)(smem + 64);                      // 1.5 KB
  float (*fstage)[128] = (float (*)[128])(smem + 1600);  // 2 KB
  int w = tid >> 6, lane = tid & 63;
  int nloc = lane & 15, grp = lane >> 4;
  for (int tile = cid; tile < 8192; tile += NCONS) {
    int mg = tile >> 5, bt = tile & 31;
    int m0 = mg * 4;
    int b = bt >> 3, t = bt & 7;
    int m = m0 + w;
    if (tid == 0) {
      for (int it = 0; it < 1000000 && aLoadAcqI(&progress[bt]) < m0 + 4; ++it)
        __builtin_amdgcn_s_sleep(8);
    }
    __syncthreads();
    if (lane == 0) {
      const float* ap = anchors + ((size_t)(bt * M + m)) * 3;
      anc_lds[w * 4 + 0] = aLoadF(ap + 0);
      anc_lds[w * 4 + 1] = aLoadF(ap + 1);
      anc_lds[w * 4 + 2] = aLoadF(ap + 2);
    }
    asm volatile("s_waitcnt lgkmcnt(0)" ::: "memory");
    __builtin_amdgcn_sched_barrier(0);
    float ax = anc_lds[w * 4 + 0];
    float ay = anc_lds[w * 4 + 1];
    float az = anc_lds[w * 4 + 2];
    for (int di = 0; di < 3; ++di) {
      int srct = t + di - 1;
      srct = srct < 0 ? 0 : (srct > 7 ? 7 : srct);
      ballq_one(xyz + ((size_t)(b * T + srct)) * N * 3, ax, ay, az,
                idx_lds + (w * 3 + di) * KNN);
    }
    asm volatile("s_waitcnt lgkmcnt(0)" ::: "memory");
    __builtin_amdgcn_sched_barrier(0);
    f32x4 acc[8];
#pragma unroll
    for (int mt = 0; mt < 8; ++mt) acc[mt] = (f32x4){0.f, 0.f, 0.f, 0.f};
    short8 pg0[2][2], pg1[2][2];
    float ppx[2][2], ppy[2][2], ppz[2][2];

#define MLOADP(BUF, DI)                                                          \
  {                                                                              \
    int srct = t + (DI)-1;                                                       \
    srct = srct < 0 ? 0 : (srct > 7 ? 7 : srct);                                 \
    const unsigned short* rf = RFFh + ((size_t)(b * T + srct)) * N * 64;         \
    const float* pts = xyz + ((size_t)(b * T + srct)) * N * 3;                   \
    const int* ipw = idx_lds + (w * 3 + (DI)) * KNN;                             \
    int n0 = ipw[nloc], n1 = ipw[16 + nloc];                                     \
    _Pragma("unroll") for (int kt = 0; kt < 2; ++kt) {                           \
      pg0[BUF][kt] = *(const short8*)(rf + (size_t)n0 * 64 + kt * 32 + grp * 8); \
      pg1[BUF][kt] = *(const short8*)(rf + (size_t)n1 * 64 + kt * 32 + grp * 8); \
    }                                                                            \
    ppx[BUF][0] = pts[n0 * 3 + 0];                                               \
    ppy[BUF][0] = pts[n0 * 3 + 1];                                               \
    ppz[BUF][0] = pts[n0 * 3 + 2];                                               \
    ppx[BUF][1] = pts[n1 * 3 + 0];                                               \
    ppy[BUF][1] = pts[n1 * 3 + 1];                                               \
    ppz[BUF][1] = pts[n1 * 3 + 2];                                               \
  }

#define MCOMPUTE(BUF, DI)                                                          \
  {                                                                                \
    int zro = 0;                                                                   \
    asm volatile("" : "+v"(zro));                                                  \
    const unsigned short* AhO = w1hi + zro;  /* global, L1/L2-resident */          \
    const unsigned short* AlO = w1lo + zro;                                        \
    const float* wdO = Wd + zro;                                                   \
    float tvv = (float)((DI)-1);                                                   \
    float dx0 = ppx[BUF][0] - ax, dy0 = ppy[BUF][0] - ay, dz0 = ppz[BUF][0] - az;  \
    float dx1 = ppx[BUF][1] - ax, dy1 = ppy[BUF][1] - ay, dz1 = ppz[BUF][1] - az;  \
    short8 Bh[2][2];                                                               \
    _Pragma("unroll") for (int kt = 0; kt < 2; ++kt) {                             \
      short8 bh0, bh1;                                                             \
      _Pragma("unroll") for (int j = 0; j < 8; ++j) {                              \
        int ch = kt * 32 + grp * 8 + j;                                            \
        float4 wr = *(const float4*)&wdO[ch * 4];                                  \
        float dd0 = fmaf(dx0, wr.x, fmaf(dy0, wr.y, fmaf(dz0, wr.z, tvv * wr.w))); \
        float dd1 = fmaf(dx1, wr.x, fmaf(dy1, wr.y, fmaf(dz1, wr.z, tvv * wr.w))); \
        float h0 = bf2f((unsigned short)pg0[BUF][kt][j]) + fmaxf(dd0, 0.f);        \
        float h1 = bf2f((unsigned short)pg1[BUF][kt][j]) + fmaxf(dd1, 0.f);        \
        bh0[j] = f2bf_rn(h0);                                                      \
        bh1[j] = f2bf_rn(h1);                                                      \
      }                                                                            \
      Bh[kt][0] = bh0;                                                             \
      Bh[kt][1] = bh1;                                                             \
    }                                                                              \
    _Pragma("unroll") for (int hf = 0; hf < 2; ++hf) {                             \
      f32x4 c[4][2];                                                               \
      _Pragma("unroll") for (int mq = 0; mq < 4; ++mq) {                           \
        c[mq][0] = (f32x4){0.f, 0.f, 0.f, 0.f};                                    \
        c[mq][1] = (f32x4){0.f, 0.f, 0.f, 0.f};                                    \
      }                                                                            \
      _Pragma("unroll") for (int kt = 0; kt < 2; ++kt) {                           \
        _Pragma("unroll") for (int mq = 0; mq < 4; ++mq) {                         \
          int fo = ((kt * 8 + hf * 4 + mq) * 64 + lane) * 8;                       \
          short8 ahf = *(const short8*)&AhO[fo];                                   \
          short8 alf = *(const short8*)&AlO[fo];                                   \
          c[mq][0] = __builtin_amdgcn_mfma_f32_16x16x32_bf16(ahf, Bh[kt][0],       \
                                                             c[mq][0], 0, 0, 0);  \
          c[mq][0] = __builtin_amdgcn_mfma_f32_16x16x32_bf16(alf, Bh[kt][0],       \
                                                             c[mq][0], 0, 0, 0);  \
          c[mq][1] = __builtin_amdgcn_mfma_f32_16x16x32_bf16(ahf, Bh[kt][1],       \
                                                             c[mq][1], 0, 0, 0);  \
          c[mq][1] = __builtin_amdgcn_mfma_f32_16x16x32_bf16(alf, Bh[kt][1],       \
                                                             c[mq][1], 0, 0, 0);  \
        }                                                                          \
      }                                                                            \
      _Pragma("unroll") for (int mq = 0; mq < 4; ++mq)                             \
          _Pragma("unroll") for (int r = 0; r < 4; ++r) {                          \
        float o = fmaxf(c[mq][0][r], c[mq][1][r]);                                 \
        o = fmaxf(o, dppf<0xB1>(o));                                               \
        o = fmaxf(o, dppf<0x4E>(o));                                               \
        o = fmaxf(o, dppf<0x141>(o));                                              \
        o = fmaxf(o, dppf<0x140>(o));                                              \
        acc[hf * 4 + mq][r] += fmaxf(o, 0.f);                                      \
      }                                                                            \
    }                                                                              \
  }

    MLOADP(0, 0)
    MLOADP(1, 1)
    MCOMPUTE(0, 0)
    MLOADP(0, 2)
    MCOMPUTE(1, 1)
    MCOMPUTE(0, 2)
#undef MLOADP
#undef MCOMPUTE

    if (nloc == 0) {
#pragma unroll
      for (int mt = 0; mt < 8; ++mt)
#pragma unroll
        for (int r = 0; r < 4; ++r)
          fstage[w][mt * 16 + grp * 4 + r] = acc[mt][r];
    }
    __syncthreads();
    if (tid < 128) {
      float4 v = make_float4(fstage[0][tid], fstage[1][tid], fstage[2][tid], fstage[3][tid]);
      *(float4*)&out_feats[((size_t)(bt * C1 + tid)) * M + m0] = v;
    }
    __syncthreads();
  }
}

// ---------------- mega kernel: 32 fps producers + 480 consumers -------------
__global__ __launch_bounds__(256) void mega_kernel(const float* __restrict__ xyz,
                                                   float* __restrict__ anchors,
                                                   const unsigned short* __restrict__ RFFh,
                                                   const unsigned short* __restrict__ w1hi,
                                                   const unsigned short* __restrict__ w1lo,
                                                   const float* __restrict__ Wd,
                                                   float* __restrict__ out_feats,
                                                   int* __restrict__ progress) {
  __shared__ __align__(16) char smem[SMEM_BYTES];
  if (blockIdx.x < 32)
    fps_body(smem, xyz, anchors, progress, blockIdx.x);
  else
    consumer_body(smem, xyz, anchors, RFFh, w1hi, w1lo, Wd, out_feats, progress,
                  blockIdx.x - 32);
}

extern "C" void kernel_launch(void* const* d_in, const int* in_sizes, int n_in,
                              void* d_out, int out_size, void* d_ws, size_t ws_size,
                              hipStream_t stream) {
  const float* xyzs = (const float*)d_in[0];
  const float* feats = (const float*)d_in[1];
  const float* Wd = (const float*)d_in[2];
  const float* Wf = (const float*)d_in[3];
  const float* W1 = (const float*)d_in[4];
  float* out_xyz = (float*)d_out;                            // (B,8,M,3)
  float* out_feats = (float*)d_out + (size_t)B * T * M * 3;  // (B,8,C1,M)
  char* ws = (char*)d_ws;
  unsigned short* RFFh = (unsigned short*)ws;                // 16.78 MB
  char* tail = ws + (size_t)B * T * N * 64 * 2;
  float* WfT = (float*)tail;                                 // 16 KB
  unsigned short* w1hi = (unsigned short*)(tail + 16384);    // 16 KB
  unsigned short* w1lo = (unsigned short*)(tail + 32768);    // 16 KB
  int* progress = (int*)(tail + 49152);                      // 32 ints
  hipMemsetAsync(progress, 0, 128, stream);                  // reset gate each call
  prep_wft<<<16, 256, 0, stream>>>(Wf, WfT);
  prep_w1frag<<<32, 256, 0, stream>>>(W1, w1hi, w1lo);
  rff_kernel<<<dim3(N / 64, B * T), 256, 0, stream>>>(feats, WfT, RFFh);
  mega_kernel<<<NBLK, 256, 0, stream>>>(xyzs, out_xyz, RFFh, w1hi, w1lo, Wd, out_feats,
                                        progress);
}

// Round 15
// 1131.416 us; speedup vs baseline: 1.1705x; 1.1705x over previous
//
#include <hip/hip_runtime.h>
#include <hip/hip_bf16.h>

constexpr int B = 4, T = 8, N = 4096, C0 = 64, C1 = 128;
constexpr int M = 1024, KNN = 32;

typedef __attribute__((ext_vector_type(8))) short short8;
typedef __attribute__((ext_vector_type(4))) float f32x4;
typedef __attribute__((ext_vector_type(2))) float f32x2;

__device__ __forceinline__ unsigned short f2bf(float x) {
  unsigned u = __float_as_uint(x);
  u = u + 0x7FFFu + ((u >> 16) & 1u);
  return (unsigned short)(u >> 16);
}
__device__ __forceinline__ float bf2f(unsigned short h) {
  return __uint_as_float((unsigned)h << 16);
}
__device__ __forceinline__ short f2bf_rn(float x) {
  union { __hip_bfloat16 b; unsigned short u; } v;
  v.b = __float2bfloat16(x);
  return (short)v.u;
}

template <int CTRL>
__device__ __forceinline__ float dppf(float x) {
  return __int_as_float(__builtin_amdgcn_update_dpp(0, __float_as_int(x), CTRL, 0xF, 0xF, true));
}
template <int CTRL>
__device__ __forceinline__ int dppi(int x) {
  return __builtin_amdgcn_update_dpp(0, x, CTRL, 0xF, 0xF, true);
}
template <int CTRL>
__device__ __forceinline__ unsigned long long dppu64(unsigned long long x) {
  unsigned lo = (unsigned)dppi<CTRL>((int)(unsigned)x);
  unsigned hi = (unsigned)dppi<CTRL>((int)(unsigned)(x >> 32));
  return ((unsigned long long)hi << 32) | lo;
}
__device__ __forceinline__ void kmerge(unsigned long long& a, unsigned long long b) {
  if (b > a) a = b;
}
__device__ __forceinline__ unsigned long long kmax(unsigned long long a, unsigned long long b) {
  return b > a ? b : a;
}

// ---------------- prep: WfT[c][o] = Wf[o][c] --------------------------------
__global__ __launch_bounds__(256) void prep_wft(const float* __restrict__ Wf,
                                                float* __restrict__ WfT) {
  int t = blockIdx.x * 256 + threadIdx.x;
  if (t < 64 * 64) WfT[t] = Wf[(t & 63) * 64 + (t >> 6)];
}

// ---------------- prep: W1 -> MFMA A-fragment-ordered bf16 hi/lo ------------
__global__ __launch_bounds__(256) void prep_w1frag(const float* __restrict__ W1,
                                                   unsigned short* __restrict__ w1hi,
                                                   unsigned short* __restrict__ w1lo) {
  int t = blockIdx.x * 256 + threadIdx.x;
  if (t >= 8192) return;
  int j = t & 7, lane = (t >> 3) & 63, mt = (t >> 9) & 7, kt = t >> 12;
  int row = mt * 16 + (lane & 15);
  int k = kt * 32 + (lane >> 4) * 8 + j;
  float v = W1[row * 64 + k];
  unsigned short hi = f2bf(v);
  w1hi[t] = hi;
  w1lo[t] = f2bf(v - bf2f(hi));
}

// ---------------- fps: 4 waves, f32x2-packed update, 6-hop DPP, 4 slots -----
__device__ void fps_body(char* smem, const float* __restrict__ xyz,
                         float* __restrict__ out_xyz, int bt) {
#pragma clang fp contract(off)
  float* xs = (float*)smem;  // 16 KB
  float* ys = xs + N;        // 16 KB
  float* zs = ys + N;        // 16 KB
  unsigned long long* wslot = (unsigned long long*)(smem + 49152);  // 2 bufs x 4
  const float* p = xyz + (size_t)bt * N * 3;
  int tid = threadIdx.x;
  int lane = tid & 63, w = tid >> 6;
  for (int i = tid; i < N; i += 256) {
    xs[i] = p[i * 3 + 0];
    ys[i] = p[i * 3 + 1];
    zs[i] = p[i * 3 + 2];
  }
  __syncthreads();
  f32x2 X2[8], Y2[8], Z2[8], D2[8];
  unsigned inv[16];
#pragma unroll
  for (int j = 0; j < 8; ++j) {
    int i0 = (2 * j) * 256 + tid, i1 = (2 * j + 1) * 256 + tid;
    X2[j] = (f32x2){xs[i0], xs[i1]};
    Y2[j] = (f32x2){ys[i0], ys[i1]};
    Z2[j] = (f32x2){zs[i0], zs[i1]};
    D2[j] = (f32x2){1e10f, 1e10f};
    inv[2 * j] = ~(unsigned)i0;
    inv[2 * j + 1] = ~(unsigned)i1;
  }
  if (tid == 0) {
    float* a0 = out_xyz + (size_t)bt * M * 3;
    a0[0] = xs[0]; a0[1] = ys[0]; a0[2] = zs[0];
  }
  int lidx = 0;
  for (int s = 1; s < M; ++s) {
    float lx = xs[lidx], ly = ys[lidx], lz = zs[lidx];
    if (tid == 0 && s > 1) {  // stream pick s-1 (coords = lp)
      float* ap = out_xyz + ((size_t)(bt * M + s - 1)) * 3;
      ap[0] = lx; ap[1] = ly; ap[2] = lz;
    }
    f32x2 l2x = (f32x2){lx, lx}, l2y = (f32x2){ly, ly}, l2z = (f32x2){lz, lz};
    unsigned long long k[16];
#pragma unroll
    for (int j = 0; j < 8; ++j) {
      f32x2 dx = X2[j] - l2x;
      f32x2 dy = Y2[j] - l2y;
      f32x2 dz = Z2[j] - l2z;
      f32x2 d = dx * dx + dy * dy + dz * dz;  // contract(off): mul+add exact
      f32x2 nd = __builtin_elementwise_min(D2[j], d);
      D2[j] = nd;
      k[2 * j] = ((unsigned long long)__float_as_uint(nd.x) << 32) | inv[2 * j];
      k[2 * j + 1] = ((unsigned long long)__float_as_uint(nd.y) << 32) | inv[2 * j + 1];
    }
#pragma unroll
    for (int st = 8; st >= 1; st >>= 1)
#pragma unroll
      for (int j = 0; j < st; ++j) kmerge(k[j], k[j + st]);
    unsigned long long best = k[0];
    kmerge(best, dppu64<0xB1>(best));
    kmerge(best, dppu64<0x4E>(best));
    kmerge(best, dppu64<0x141>(best));
    kmerge(best, dppu64<0x140>(best));
    kmerge(best, dppu64<0x142>(best));  // row_bcast15
    kmerge(best, dppu64<0x143>(best));  // row_bcast31 -> lanes 48-63 = wave max
    int buf = s & 1;
    if (lane == 63) wslot[buf * 4 + w] = best;
    asm volatile("s_waitcnt lgkmcnt(0)" ::: "memory");
    __builtin_amdgcn_s_barrier();
    __builtin_amdgcn_sched_barrier(0);
    const ulonglong2* ws2 = (const ulonglong2*)&wslot[buf * 4];
    ulonglong2 a0 = ws2[0], a1 = ws2[1];
    unsigned long long g = kmax(kmax(a0.x, a0.y), kmax(a1.x, a1.y));
    lidx = (int)(~(unsigned)g);
  }
  if (tid == 0) {
    float* ap = out_xyz + ((size_t)(bt * M + M - 1)) * 3;
    ap[0] = xs[lidx]; ap[1] = ys[lidx]; ap[2] = zs[lidx];
  }
}

// ---------------- rff tile: RFFh[n] = bf16(relu(Wf @ f_n)) ------------------
__device__ void rff_body(char* smem, const float* __restrict__ f,
                         const float* __restrict__ WfT, unsigned short* __restrict__ RFFh,
                         int rid) {
  float (*tile)[65] = (float (*)[65])smem;  // 16.6 KB
  int bt = rid >> 6;
  int n0 = (rid & 63) * 64;
  const float* src = f + (size_t)bt * C0 * N;
  int tx = threadIdx.x & 63, ty = threadIdx.x >> 6;
  for (int r = ty; r < 64; r += 4)
    tile[r][tx] = src[(size_t)r * N + n0 + tx];
  __syncthreads();
  float acc[16];
#pragma unroll
  for (int oo = 0; oo < 16; ++oo) acc[oo] = 0.f;
  int obase = ty * 16;
#pragma unroll 4
  for (int c = 0; c < 64; ++c) {
    float fv = tile[c][tx];
    const float* wr = WfT + c * 64 + obase;
#pragma unroll
    for (int oo = 0; oo < 16; ++oo) acc[oo] = fmaf(fv, wr[oo], acc[oo]);
  }
  __syncthreads();
#pragma unroll
  for (int oo = 0; oo < 16; ++oo) tile[obase + oo][tx] = fmaxf(acc[oo], 0.f);
  __syncthreads();
  unsigned short* dst = RFFh + ((size_t)bt * N + n0) * 64;
  for (int r = ty; r < 64; r += 4)
    dst[(size_t)r * 64 + tx] = f2bf(tile[tx][r]);
}

__global__ __launch_bounds__(256) void fps_rff_kernel(const float* __restrict__ xyz,
                                                      float* __restrict__ out_xyz,
                                                      const float* __restrict__ feats,
                                                      const float* __restrict__ WfT,
                                                      unsigned short* __restrict__ RFFh) {
  __shared__ __align__(16) char smem[49152 + 256];
  if (blockIdx.x < 32)
    fps_body(smem, xyz, out_xyz, blockIdx.x);
  else
    rff_body(smem, feats, WfT, RFFh, blockIdx.x - 32);
}

// ---------------- ball query: one wave, result into LDS ---------------------
__device__ void ballq_one(const float* __restrict__ pts, float ax, float ay, float az,
                          int* outp) {
  const float R2 = 0.04f;
  int lane = threadIdx.x & 63;
  int cnt = 0, first = 0;
  for (int c = 0; c < N / 64 && cnt < KNN; ++c) {
    int pi = c * 64 + lane;
    const float* pp = pts + (size_t)pi * 3;
    float dx = __fsub_rn(ax, pp[0]);
    float dy = __fsub_rn(ay, pp[1]);
    float dz = __fsub_rn(az, pp[2]);
    float d2 = __fadd_rn(__fadd_rn(__fmul_rn(dx, dx), __fmul_rn(dy, dy)), __fmul_rn(dz, dz));
    bool hit = d2 < R2;
    unsigned long long mask = __ballot(hit);
    if (cnt == 0 && mask) first = c * 64 + (int)__builtin_ctzll(mask);
    int prefix = (int)__popcll(mask & ((1ull << lane) - 1ull));
    int slot = cnt + prefix;
    if (hit && slot < KNN) outp[slot] = pi;
    cnt += (int)__popcll(mask);
  }
  int cntK = cnt < KNN ? cnt : KNN;
  int fill = (cnt == 0) ? 0 : first;
  if (lane < KNN && lane >= cntK) outp[lane] = fill;
}

// ---------------- fused ballq + gather(bf16) + dfeat + MFMA layer2 ----------
// wave = anchor; ballq results stay in LDS (idxbuf round-trip deleted).
__global__ __launch_bounds__(256) void bqmlp_kernel(const float* __restrict__ xyz,
                                                    const unsigned short* __restrict__ RFFh,
                                                    const unsigned short* __restrict__ w1hi,
                                                    const unsigned short* __restrict__ w1lo,
                                                    const float* __restrict__ Wd,
                                                    const float* __restrict__ anchors,
                                                    float* __restrict__ out_feats) {
  __shared__ unsigned short Ah[8192];
  __shared__ unsigned short Al[8192];
  __shared__ float wd_l[256];
  __shared__ int idx_lds[4][3][KNN];
  __shared__ float fstage[4][128];
  int tid = threadIdx.x;
  {
    uint4* dh = (uint4*)Ah;
    const uint4* sh = (const uint4*)w1hi;
    uint4* dl = (uint4*)Al;
    const uint4* sl = (const uint4*)w1lo;
    for (int i = tid; i < 1024; i += 256) { dh[i] = sh[i]; dl[i] = sl[i]; }
    wd_l[tid] = Wd[tid];
  }
  __syncthreads();
  int w = tid >> 6, lane = tid & 63;
  int nloc = lane & 15, grp = lane >> 4;
  int bid = blockIdx.x;
  int swz = ((bid & 7) << 10) | (bid >> 3);  // XCD-aware, bijective for 8192
  int bt = swz >> 8;
  int m0 = (swz & 255) * 4;
  int m = m0 + w;
  int b = bt >> 3, t = bt & 7;
  int aoff = __builtin_amdgcn_readfirstlane(bt * M + m);
  float ax = anchors[(size_t)aoff * 3 + 0];
  float ay = anchors[(size_t)aoff * 3 + 1];
  float az = anchors[(size_t)aoff * 3 + 2];
  for (int di = 0; di < 3; ++di) {
    int srct = t + di - 1;
    srct = srct < 0 ? 0 : (srct > 7 ? 7 : srct);
    ballq_one(xyz + ((size_t)(b * T + srct)) * N * 3, ax, ay, az, idx_lds[w][di]);
  }
  asm volatile("s_waitcnt lgkmcnt(0)" ::: "memory");
  __builtin_amdgcn_sched_barrier(0);
  f32x4 acc[8];
#pragma unroll
  for (int mt = 0; mt < 8; ++mt) acc[mt] = (f32x4){0.f, 0.f, 0.f, 0.f};
  short8 pg0[2][2], pg1[2][2];
  float ppx[2][2], ppy[2][2], ppz[2][2];

#define MLOADP(BUF, DI)                                                          \
  {                                                                              \
    int srct = t + (DI)-1;                                                       \
    srct = srct < 0 ? 0 : (srct > 7 ? 7 : srct);                                 \
    const unsigned short* rf = RFFh + ((size_t)(b * T + srct)) * N * 64;         \
    const float* pts = xyz + ((size_t)(b * T + srct)) * N * 3;                   \
    const int* ipw = idx_lds[w][DI];                                             \
    int n0 = ipw[nloc], n1 = ipw[16 + nloc];                                     \
    _Pragma("unroll") for (int kt = 0; kt < 2; ++kt) {                           \
      pg0[BUF][kt] = *(const short8*)(rf + (size_t)n0 * 64 + kt * 32 + grp * 8); \
      pg1[BUF][kt] = *(const short8*)(rf + (size_t)n1 * 64 + kt * 32 + grp * 8); \
    }                                                                            \
    ppx[BUF][0] = pts[n0 * 3 + 0];                                               \
    ppy[BUF][0] = pts[n0 * 3 + 1];                                               \
    ppz[BUF][0] = pts[n0 * 3 + 2];                                               \
    ppx[BUF][1] = pts[n1 * 3 + 0];                                               \
    ppy[BUF][1] = pts[n1 * 3 + 1];                                               \
    ppz[BUF][1] = pts[n1 * 3 + 2];                                               \
  }

#define MCOMPUTE(BUF, DI)                                                          \
  {                                                                                \
    int zro = 0;                                                                   \
    asm volatile("" : "+v"(zro));                                                  \
    const unsigned short* AhO = Ah + zro;                                          \
    const unsigned short* AlO = Al + zro;                                          \
    const float* wdO = (const float*)wd_l + zro;                                   \
    float tvv = (float)((DI)-1);                                                   \
    float dx0 = ppx[BUF][0] - ax, dy0 = ppy[BUF][0] - ay, dz0 = ppz[BUF][0] - az;  \
    float dx1 = ppx[BUF][1] - ax, dy1 = ppy[BUF][1] - ay, dz1 = ppz[BUF][1] - az;  \
    short8 Bh[2][2];                                                               \
    _Pragma("unroll") for (int kt = 0; kt < 2; ++kt) {                             \
      short8 bh0, bh1;                                                             \
      _Pragma("unroll") for (int j = 0; j < 8; ++j) {                              \
        int ch = kt * 32 + grp * 8 + j;                                            \
        float4 wr = *(const float4*)&wdO[ch * 4];                                  \
        float dd0 = fmaf(dx0, wr.x, fmaf(dy0, wr.y, fmaf(dz0, wr.z, tvv * wr.w))); \
        float dd1 = fmaf(dx1, wr.x, fmaf(dy1, wr.y, fmaf(dz1, wr.z, tvv * wr.w))); \
        float h0 = bf2f((unsigned short)pg0[BUF][kt][j]) + fmaxf(dd0, 0.f);        \
        float h1 = bf2f((unsigned short)pg1[BUF][kt][j]) + fmaxf(dd1, 0.f);        \
        bh0[j] = f2bf_rn(h0);                                                      \
        bh1[j] = f2bf_rn(h1);                                                      \
      }                                                                            \
      Bh[kt][0] = bh0;                                                             \
      Bh[kt][1] = bh1;                                                             \
    }                                                                              \
    _Pragma("unroll") for (int hf = 0; hf < 2; ++hf) {                             \
      f32x4 c[4][2];                                                               \
      _Pragma("unroll") for (int mq = 0; mq < 4; ++mq) {                           \
        c[mq][0] = (f32x4){0.f, 0.f, 0.f, 0.f};                                    \
        c[mq][1] = (f32x4){0.f, 0.f, 0.f, 0.f};                                    \
      }                                                                            \
      _Pragma("unroll") for (int kt = 0; kt < 2; ++kt) {                           \
        _Pragma("unroll") for (int mq = 0; mq < 4; ++mq) {                         \
          int fo = ((kt * 8 + hf * 4 + mq) * 64 + lane) * 8;                       \
          short8 ahf = *(const short8*)&AhO[fo];                                   \
          short8 alf = *(const short8*)&AlO[fo];                                   \
          c[mq][0] = __builtin_amdgcn_mfma_f32_16x16x32_bf16(ahf, Bh[kt][0],       \
                                                             c[mq][0], 0, 0, 0);  \
          c[mq][0] = __builtin_amdgcn_mfma_f32_16x16x32_bf16(alf, Bh[kt][0],       \
                                                             c[mq][0], 0, 0, 0);  \
          c[mq][1] = __builtin_amdgcn_mfma_f32_16x16x32_bf16(ahf, Bh[kt][1],       \
                                                             c[mq][1], 0, 0, 0);  \
          c[mq][1] = __builtin_amdgcn_mfma_f32_16x16x32_bf16(alf, Bh[kt][1],       \
                                                             c[mq][1], 0, 0, 0);  \
        }                                                                          \
      }                                                                            \
      _Pragma("unroll") for (int mq = 0; mq < 4; ++mq)                             \
          _Pragma("unroll") for (int r = 0; r < 4; ++r) {                          \
        float o = fmaxf(c[mq][0][r], c[mq][1][r]);                                 \
        o = fmaxf(o, dppf<0xB1>(o));                                               \
        o = fmaxf(o, dppf<0x4E>(o));                                               \
        o = fmaxf(o, dppf<0x141>(o));                                              \
        o = fmaxf(o, dppf<0x140>(o));                                              \
        acc[hf * 4 + mq][r] += fmaxf(o, 0.f);                                      \
      }                                                                            \
    }                                                                              \
  }

  MLOADP(0, 0)
  MLOADP(1, 1)
  MCOMPUTE(0, 0)
  MLOADP(0, 2)
  MCOMPUTE(1, 1)
  MCOMPUTE(0, 2)
#undef MLOADP
#undef MCOMPUTE

  if (nloc == 0) {
#pragma unroll
    for (int mt = 0; mt < 8; ++mt)
#pragma unroll
      for (int r = 0; r < 4; ++r)
        fstage[w][mt * 16 + grp * 4 + r] = acc[mt][r];
  }
  __syncthreads();
  if (tid < 128) {
    float4 v = make_float4(fstage[0][tid], fstage[1][tid], fstage[2][tid], fstage[3][tid]);
    *(float4*)&out_feats[((size_t)(bt * C1 + tid)) * M + m0] = v;
  }
}

extern "C" void kernel_launch(void* const* d_in, const int* in_sizes, int n_in,
                              void* d_out, int out_size, void* d_ws, size_t ws_size,
                              hipStream_t stream) {
  const float* xyzs = (const float*)d_in[0];
  const float* feats = (const float*)d_in[1];
  const float* Wd = (const float*)d_in[2];
  const float* Wf = (const float*)d_in[3];
  const float* W1 = (const float*)d_in[4];
  float* out_xyz = (float*)d_out;                            // (B,8,M,3)
  float* out_feats = (float*)d_out + (size_t)B * T * M * 3;  // (B,8,C1,M)
  char* ws = (char*)d_ws;
  unsigned short* RFFh = (unsigned short*)ws;                // 16.78 MB
  char* tail = ws + (size_t)B * T * N * 64 * 2;
  float* WfT = (float*)tail;                                 // 16 KB
  unsigned short* w1hi = (unsigned short*)(tail + 16384);    // 16 KB
  unsigned short* w1lo = (unsigned short*)(tail + 32768);    // 16 KB
  prep_wft<<<16, 256, 0, stream>>>(Wf, WfT);
  prep_w1frag<<<32, 256, 0, stream>>>(W1, w1hi, w1lo);
  fps_rff_kernel<<<32 + 2048, 256, 0, stream>>>(xyzs, out_xyz, feats, WfT, RFFh);
  bqmlp_kernel<<<B * T * M / 4, 256, 0, stream>>>(xyzs, RFFh, w1hi, w1lo, Wd, out_xyz,
                                                  out_feats);
}

// Round 16
// 928.900 us; speedup vs baseline: 1.4257x; 1.2180x over previous
//
#include <hip/hip_runtime.h>
#include <hip/hip_bf16.h>

constexpr int B = 4, T = 8, N = 4096, C0 = 64, C1 = 128;
constexpr int M = 1024, KNN = 32;

typedef __attribute__((ext_vector_type(8))) short short8;
typedef __attribute__((ext_vector_type(4))) float f32x4;
typedef __attribute__((ext_vector_type(2))) float f32x2;

__device__ __forceinline__ unsigned short f2bf(float x) {
  unsigned u = __float_as_uint(x);
  u = u + 0x7FFFu + ((u >> 16) & 1u);
  return (unsigned short)(u >> 16);
}
__device__ __forceinline__ float bf2f(unsigned short h) {
  return __uint_as_float((unsigned)h << 16);
}
__device__ __forceinline__ short f2bf_rn(float x) {
  union { __hip_bfloat16 b; unsigned short u; } v;
  v.b = __float2bfloat16(x);
  return (short)v.u;
}

template <int CTRL>
__device__ __forceinline__ float dppf(float x) {
  return __int_as_float(__builtin_amdgcn_update_dpp(0, __float_as_int(x), CTRL, 0xF, 0xF, true));
}
template <int CTRL>
__device__ __forceinline__ int dppi(int x) {
  return __builtin_amdgcn_update_dpp(0, x, CTRL, 0xF, 0xF, true);
}
template <int CTRL>
__device__ __forceinline__ unsigned long long dppu64(unsigned long long x) {
  unsigned lo = (unsigned)dppi<CTRL>((int)(unsigned)x);
  unsigned hi = (unsigned)dppi<CTRL>((int)(unsigned)(x >> 32));
  return ((unsigned long long)hi << 32) | lo;
}
__device__ __forceinline__ void kmerge(unsigned long long& a, unsigned long long b) {
  if (b > a) a = b;
}
__device__ __forceinline__ unsigned long long kmax(unsigned long long a, unsigned long long b) {
  return b > a ? b : a;
}

// ---------------- prep: WfT[c][o] = Wf[o][c] --------------------------------
__global__ __launch_bounds__(256) void prep_wft(const float* __restrict__ Wf,
                                                float* __restrict__ WfT) {
  int t = blockIdx.x * 256 + threadIdx.x;
  if (t < 64 * 64) WfT[t] = Wf[(t & 63) * 64 + (t >> 6)];
}

// ---------------- prep: W1 -> MFMA A-fragment-ordered bf16 hi/lo ------------
__global__ __launch_bounds__(256) void prep_w1frag(const float* __restrict__ W1,
                                                   unsigned short* __restrict__ w1hi,
                                                   unsigned short* __restrict__ w1lo) {
  int t = blockIdx.x * 256 + threadIdx.x;
  if (t >= 8192) return;
  int j = t & 7, lane = (t >> 3) & 63, mt = (t >> 9) & 7, kt = t >> 12;
  int row = mt * 16 + (lane & 15);
  int k = kt * 32 + (lane >> 4) * 8 + j;
  float v = W1[row * 64 + k];
  unsigned short hi = f2bf(v);
  w1hi[t] = hi;
  w1lo[t] = f2bf(v - bf2f(hi));
}

// ---------------- fps v5: 4 waves, f32x2-packed update, 6-hop DPP, 4 slots --
__device__ void fps_body(char* smem, const float* __restrict__ xyz,
                         float* __restrict__ out_xyz, int bt) {
#pragma clang fp contract(off)
  float* xs = (float*)smem;  // 16 KB
  float* ys = xs + N;        // 16 KB
  float* zs = ys + N;        // 16 KB
  unsigned long long* wslot = (unsigned long long*)(smem + 49152);  // 2 bufs x 4
  const float* p = xyz + (size_t)bt * N * 3;
  int tid = threadIdx.x;
  int lane = tid & 63, w = tid >> 6;
  for (int i = tid; i < N; i += 256) {
    xs[i] = p[i * 3 + 0];
    ys[i] = p[i * 3 + 1];
    zs[i] = p[i * 3 + 2];
  }
  __syncthreads();
  f32x2 X2[8], Y2[8], Z2[8], D2[8];
  unsigned inv[16];
#pragma unroll
  for (int j = 0; j < 8; ++j) {
    int i0 = (2 * j) * 256 + tid, i1 = (2 * j + 1) * 256 + tid;
    X2[j] = (f32x2){xs[i0], xs[i1]};
    Y2[j] = (f32x2){ys[i0], ys[i1]};
    Z2[j] = (f32x2){zs[i0], zs[i1]};
    D2[j] = (f32x2){1e10f, 1e10f};
    inv[2 * j] = ~(unsigned)i0;
    inv[2 * j + 1] = ~(unsigned)i1;
  }
  if (tid == 0) {
    float* a0 = out_xyz + (size_t)bt * M * 3;
    a0[0] = xs[0]; a0[1] = ys[0]; a0[2] = zs[0];
  }
  int lidx = 0;
  for (int s = 1; s < M; ++s) {
    float lx = xs[lidx], ly = ys[lidx], lz = zs[lidx];
    if (tid == 0 && s > 1) {  // stream pick s-1 (coords = lp); store is async
      float* ap = out_xyz + ((size_t)(bt * M + s - 1)) * 3;
      ap[0] = lx; ap[1] = ly; ap[2] = lz;
    }
    f32x2 l2x = (f32x2){lx, lx}, l2y = (f32x2){ly, ly}, l2z = (f32x2){lz, lz};
    unsigned long long k[16];
#pragma unroll
    for (int j = 0; j < 8; ++j) {
      f32x2 dx = X2[j] - l2x;
      f32x2 dy = Y2[j] - l2y;
      f32x2 dz = Z2[j] - l2z;
      f32x2 d = dx * dx + dy * dy + dz * dz;  // contract(off): exact mul+add
      f32x2 nd = __builtin_elementwise_min(D2[j], d);
      D2[j] = nd;
      k[2 * j] = ((unsigned long long)__float_as_uint(nd.x) << 32) | inv[2 * j];
      k[2 * j + 1] = ((unsigned long long)__float_as_uint(nd.y) << 32) | inv[2 * j + 1];
    }
#pragma unroll
    for (int st = 8; st >= 1; st >>= 1)
#pragma unroll
      for (int j = 0; j < st; ++j) kmerge(k[j], k[j + st]);
    unsigned long long best = k[0];
    kmerge(best, dppu64<0xB1>(best));
    kmerge(best, dppu64<0x4E>(best));
    kmerge(best, dppu64<0x141>(best));
    kmerge(best, dppu64<0x140>(best));
    kmerge(best, dppu64<0x142>(best));  // row_bcast15
    kmerge(best, dppu64<0x143>(best));  // row_bcast31 -> lanes 48-63 = wave max
    int buf = s & 1;
    if (lane == 63) wslot[buf * 4 + w] = best;
    asm volatile("s_waitcnt lgkmcnt(0)" ::: "memory");
    __builtin_amdgcn_s_barrier();
    __builtin_amdgcn_sched_barrier(0);
    const ulonglong2* ws2 = (const ulonglong2*)&wslot[buf * 4];
    ulonglong2 a0 = ws2[0], a1 = ws2[1];
    unsigned long long g = kmax(kmax(a0.x, a0.y), kmax(a1.x, a1.y));
    lidx = (int)(~(unsigned)g);
  }
  if (tid == 0) {
    float* ap = out_xyz + ((size_t)(bt * M + M - 1)) * 3;
    ap[0] = xs[lidx]; ap[1] = ys[lidx]; ap[2] = zs[lidx];
  }
}

// ---------------- rff tile: RFFh[n] = bf16(relu(Wf @ f_n)) ------------------
__device__ void rff_body(char* smem, const float* __restrict__ f,
                         const float* __restrict__ WfT, unsigned short* __restrict__ RFFh,
                         int rid) {
  float (*tile)[65] = (float (*)[65])smem;  // 16.6 KB
  int bt = rid >> 6;
  int n0 = (rid & 63) * 64;
  const float* src = f + (size_t)bt * C0 * N;
  int tx = threadIdx.x & 63, ty = threadIdx.x >> 6;
  for (int r = ty; r < 64; r += 4)
    tile[r][tx] = src[(size_t)r * N + n0 + tx];
  __syncthreads();
  float acc[16];
#pragma unroll
  for (int oo = 0; oo < 16; ++oo) acc[oo] = 0.f;
  int obase = ty * 16;
#pragma unroll 4
  for (int c = 0; c < 64; ++c) {
    float fv = tile[c][tx];
    const float* wr = WfT + c * 64 + obase;
#pragma unroll
    for (int oo = 0; oo < 16; ++oo) acc[oo] = fmaf(fv, wr[oo], acc[oo]);
  }
  __syncthreads();
#pragma unroll
  for (int oo = 0; oo < 16; ++oo) tile[obase + oo][tx] = fmaxf(acc[oo], 0.f);
  __syncthreads();
  unsigned short* dst = RFFh + ((size_t)bt * N + n0) * 64;
  for (int r = ty; r < 64; r += 4)
    dst[(size_t)r * 64 + tx] = f2bf(tile[tx][r]);
}

__global__ __launch_bounds__(256) void fps_rff_kernel(const float* __restrict__ xyz,
                                                      float* __restrict__ out_xyz,
                                                      const float* __restrict__ feats,
                                                      const float* __restrict__ WfT,
                                                      unsigned short* __restrict__ RFFh) {
  __shared__ __align__(16) char smem[49152 + 256];
  if (blockIdx.x < 32)
    fps_body(smem, xyz, out_xyz, blockIdx.x);
  else
    rff_body(smem, feats, WfT, RFFh, blockIdx.x - 32);
}

// ---------------- ball query: one wave per (b,t,di,m), zero LDS -------------
__global__ __launch_bounds__(256) void ballq_kernel(const float* __restrict__ xyz,
                                                    const float* __restrict__ anchors,
                                                    int* __restrict__ idxbuf) {
  const float R2 = 0.04f;
  int w = threadIdx.x >> 6, lane = threadIdx.x & 63;
  int q = blockIdx.x * 4 + w;
  int m = q & (M - 1);
  int di = (q >> 10) % 3;
  int bt = q / (M * 3);
  int b = bt >> 3, t = bt & 7;
  int srct = t + di - 1;
  srct = srct < 0 ? 0 : (srct > 7 ? 7 : srct);
  const float* anc = anchors + ((size_t)(bt * M + m)) * 3;
  float ax = anc[0], ay = anc[1], az = anc[2];
  const float* pts = xyz + ((size_t)(b * T + srct)) * N * 3;
  int* outp = idxbuf + (size_t)q * KNN;
  int cnt = 0, first = 0;
  for (int c = 0; c < N / 64 && cnt < KNN; ++c) {
    int pi = c * 64 + lane;
    const float* pp = pts + (size_t)pi * 3;
    float dx = __fsub_rn(ax, pp[0]);
    float dy = __fsub_rn(ay, pp[1]);
    float dz = __fsub_rn(az, pp[2]);
    float d2 = __fadd_rn(__fadd_rn(__fmul_rn(dx, dx), __fmul_rn(dy, dy)), __fmul_rn(dz, dz));
    bool hit = d2 < R2;
    unsigned long long mask = __ballot(hit);
    if (cnt == 0 && mask) first = c * 64 + (int)__builtin_ctzll(mask);
    int prefix = (int)__popcll(mask & ((1ull << lane) - 1ull));
    int slot = cnt + prefix;
    if (hit && slot < KNN) outp[slot] = pi;
    cnt += (int)__popcll(mask);
  }
  int cntK = cnt < KNN ? cnt : KNN;
  int fill = (cnt == 0) ? 0 : first;
  if (lane < KNN && lane >= cntK) outp[lane] = fill;
}

// ---------------- fused gather(bf16) + dfeat + MFMA layer2 (R10-proven) -----
__global__ __launch_bounds__(256) void mlp_kernel(const float* __restrict__ xyz,
                                                  const unsigned short* __restrict__ RFFh,
                                                  const unsigned short* __restrict__ w1hi,
                                                  const unsigned short* __restrict__ w1lo,
                                                  const float* __restrict__ Wd,
                                                  const float* __restrict__ anchors,
                                                  const int* __restrict__ idxbuf,
                                                  float* __restrict__ out_feats) {
  __shared__ unsigned short Ah[8192];
  __shared__ unsigned short Al[8192];
  __shared__ float wd_l[256];
  __shared__ float fstage[4][128];
  int tid = threadIdx.x;
  {
    uint4* dh = (uint4*)Ah;
    const uint4* sh = (const uint4*)w1hi;
    uint4* dl = (uint4*)Al;
    const uint4* sl = (const uint4*)w1lo;
    for (int i = tid; i < 1024; i += 256) { dh[i] = sh[i]; dl[i] = sl[i]; }
    wd_l[tid] = Wd[tid];
  }
  __syncthreads();
  int w = tid >> 6, lane = tid & 63;
  int nloc = lane & 15, grp = lane >> 4;
  // XCD-aware swizzle: 8192 blocks, 8 XCDs -> each XCD gets 1024 contiguous
  int bid = blockIdx.x;
  int swz = ((bid & 7) << 10) | (bid >> 3);
  int bt = swz >> 8;
  int m0 = (swz & 255) * 4;
  int m = m0 + w;
  int b = bt >> 3, t = bt & 7;
  int aoff = __builtin_amdgcn_readfirstlane(bt * M + m);
  float ax = anchors[(size_t)aoff * 3 + 0];
  float ay = anchors[(size_t)aoff * 3 + 1];
  float az = anchors[(size_t)aoff * 3 + 2];
  f32x4 acc[8];
#pragma unroll
  for (int mt = 0; mt < 8; ++mt) acc[mt] = (f32x4){0.f, 0.f, 0.f, 0.f};

  short8 pg0[2][2], pg1[2][2];  // [buf][kt] bf16 rff fragments
  float ppx[2][2], ppy[2][2], ppz[2][2];

#define MLOADP(BUF, DI)                                                        \
  {                                                                            \
    int srct = t + (DI)-1;                                                     \
    srct = srct < 0 ? 0 : (srct > 7 ? 7 : srct);                               \
    const unsigned short* rf = RFFh + ((size_t)(b * T + srct)) * N * 64;       \
    const float* pts = xyz + ((size_t)(b * T + srct)) * N * 3;                 \
    const int* ip = idxbuf + ((size_t)((bt * 3 + (DI)) * M + m)) * KNN;        \
    int n0 = ip[nloc], n1 = ip[16 + nloc];                                     \
    _Pragma("unroll") for (int kt = 0; kt < 2; ++kt) {                         \
      pg0[BUF][kt] = *(const short8*)(rf + (size_t)n0 * 64 + kt * 32 + grp * 8); \
      pg1[BUF][kt] = *(const short8*)(rf + (size_t)n1 * 64 + kt * 32 + grp * 8); \
    }                                                                          \
    ppx[BUF][0] = pts[n0 * 3 + 0];                                             \
    ppy[BUF][0] = pts[n0 * 3 + 1];                                             \
    ppz[BUF][0] = pts[n0 * 3 + 2];                                             \
    ppx[BUF][1] = pts[n1 * 3 + 0];                                             \
    ppy[BUF][1] = pts[n1 * 3 + 1];                                             \
    ppz[BUF][1] = pts[n1 * 3 + 2];                                             \
  }

#define MCOMPUTE(BUF, DI)                                                      \
  {                                                                            \
    int zro = 0;                                                               \
    asm volatile("" : "+v"(zro));                                              \
    const unsigned short* AhO = Ah + zro;                                      \
    const unsigned short* AlO = Al + zro;                                      \
    const float* wdO = (const float*)wd_l + zro;                               \
    float tvv = (float)((DI)-1);                                               \
    float dx0 = ppx[BUF][0] - ax, dy0 = ppy[BUF][0] - ay, dz0 = ppz[BUF][0] - az; \
    float dx1 = ppx[BUF][1] - ax, dy1 = ppy[BUF][1] - ay, dz1 = ppz[BUF][1] - az; \
    short8 Bh[2][2]; /* [kt][nt] */                                            \
    _Pragma("unroll") for (int kt = 0; kt < 2; ++kt) {                         \
      short8 bh0, bh1;                                                         \
      _Pragma("unroll") for (int j = 0; j < 8; ++j) {                          \
        int ch = kt * 32 + grp * 8 + j;                                        \
        float4 wr = *(const float4*)&wdO[ch * 4];                              \
        float dd0 = fmaf(dx0, wr.x, fmaf(dy0, wr.y, fmaf(dz0, wr.z, tvv * wr.w))); \
        float dd1 = fmaf(dx1, wr.x, fmaf(dy1, wr.y, fmaf(dz1, wr.z, tvv * wr.w))); \
        float h0 = bf2f((unsigned short)pg0[BUF][kt][j]) + fmaxf(dd0, 0.f);    \
        float h1 = bf2f((unsigned short)pg1[BUF][kt][j]) + fmaxf(dd1, 0.f);    \
        bh0[j] = f2bf_rn(h0);                                                  \
        bh1[j] = f2bf_rn(h1);                                                  \
      }                                                                        \
      Bh[kt][0] = bh0;                                                         \
      Bh[kt][1] = bh1;                                                         \
    }                                                                          \
    _Pragma("unroll") for (int hf = 0; hf < 2; ++hf) {                         \
      f32x4 c[4][2];                                                           \
      _Pragma("unroll") for (int mq = 0; mq < 4; ++mq) {                       \
        c[mq][0] = (f32x4){0.f, 0.f, 0.f, 0.f};                                \
        c[mq][1] = (f32x4){0.f, 0.f, 0.f, 0.f};                                \
      }                                                                        \
      _Pragma("unroll") for (int kt = 0; kt < 2; ++kt) {                       \
        _Pragma("unroll") for (int mq = 0; mq < 4; ++mq) {                     \
          int fo = ((kt * 8 + hf * 4 + mq) * 64 + lane) * 8;                   \
          short8 ahf = *(const short8*)&AhO[fo];                               \
          short8 alf = *(const short8*)&AlO[fo];                               \
          c[mq][0] =                                                           \
              __builtin_amdgcn_mfma_f32_16x16x32_bf16(ahf, Bh[kt][0], c[mq][0], 0, 0, 0); \
          c[mq][0] =                                                           \
              __builtin_amdgcn_mfma_f32_16x16x32_bf16(alf, Bh[kt][0], c[mq][0], 0, 0, 0); \
          c[mq][1] =                                                           \
              __builtin_amdgcn_mfma_f32_16x16x32_bf16(ahf, Bh[kt][1], c[mq][1], 0, 0, 0); \
          c[mq][1] =                                                           \
              __builtin_amdgcn_mfma_f32_16x16x32_bf16(alf, Bh[kt][1], c[mq][1], 0, 0, 0); \
        }                                                                      \
      }                                                                        \
      _Pragma("unroll") for (int mq = 0; mq < 4; ++mq)                         \
          _Pragma("unroll") for (int r = 0; r < 4; ++r) {                      \
        float o = fmaxf(c[mq][0][r], c[mq][1][r]);                             \
        o = fmaxf(o, dppf<0xB1>(o));                                           \
        o = fmaxf(o, dppf<0x4E>(o));                                           \
        o = fmaxf(o, dppf<0x141>(o));                                          \
        o = fmaxf(o, dppf<0x140>(o));                                          \
        acc[hf * 4 + mq][r] += fmaxf(o, 0.f);                                  \
      }                                                                        \
    }                                                                          \
  }

  MLOADP(0, 0)
  MLOADP(1, 1)
  MCOMPUTE(0, 0)
  MLOADP(0, 2)
  MCOMPUTE(1, 1)
  MCOMPUTE(0, 2)
#undef MLOADP
#undef MCOMPUTE

  if (nloc == 0) {
#pragma unroll
    for (int mt = 0; mt < 8; ++mt)
#pragma unroll
      for (int r = 0; r < 4; ++r)
        fstage[w][mt * 16 + grp * 4 + r] = acc[mt][r];
  }
  __syncthreads();
  if (tid < 128) {
    float4 v = make_float4(fstage[0][tid], fstage[1][tid], fstage[2][tid], fstage[3][tid]);
    *(float4*)&out_feats[((size_t)(bt * C1 + tid)) * M + m0] = v;
  }
}

extern "C" void kernel_launch(void* const* d_in, const int* in_sizes, int n_in,
                              void* d_out, int out_size, void* d_ws, size_t ws_size,
                              hipStream_t stream) {
  const float* xyzs = (const float*)d_in[0];
  const float* feats = (const float*)d_in[1];
  const float* Wd = (const float*)d_in[2];
  const float* Wf = (const float*)d_in[3];
  const float* W1 = (const float*)d_in[4];
  float* out_xyz = (float*)d_out;                            // (B,8,M,3)
  float* out_feats = (float*)d_out + (size_t)B * T * M * 3;  // (B,8,C1,M)
  char* ws = (char*)d_ws;
  unsigned short* RFFh = (unsigned short*)ws;                       // 16.78 MB
  int* idxbuf = (int*)(ws + (size_t)B * T * N * 64 * 2);            // 12.58 MB
  char* tail = ws + (size_t)B * T * N * 64 * 2 + (size_t)B * T * 3 * M * KNN * 4;
  float* WfT = (float*)tail;                                        // 16 KB
  unsigned short* w1hi = (unsigned short*)(tail + 16384);           // 16 KB
  unsigned short* w1lo = (unsigned short*)(tail + 32768);           // 16 KB
  prep_wft<<<16, 256, 0, stream>>>(Wf, WfT);
  prep_w1frag<<<32, 256, 0, stream>>>(W1, w1hi, w1lo);
  fps_rff_kernel<<<32 + 2048, 256, 0, stream>>>(xyzs, out_xyz, feats, WfT, RFFh);
  ballq_kernel<<<(B * T * 3 * M) / 4, 256, 0, stream>>>(xyzs, out_xyz, idxbuf);
  mlp_kernel<<<(B * T * M) / 4, 256, 0, stream>>>(xyzs, RFFh, w1hi, w1lo, Wd, out_xyz,
                                                  idxbuf, out_feats);
}